// Round 1
// baseline (1190.206 us; speedup 1.0000x reference)
//
#include <hip/hip_runtime.h>
#include <math.h>

#define NN 50000
#define NE 800000
#define FEAT 64
#define HID 4096
#define NGATES 16384
#define NEG_SLOPE 0.2f
#define T_STEPS 3

__device__ __forceinline__ void atomicMaxF(float* addr, float val) {
    if (val >= 0.f) atomicMax((int*)addr, __float_as_int(val));
    else atomicMin((unsigned int*)addr, __float_as_uint(val));
}

// h_state <- W0, c_state <- 0
__global__ void k_init(const float* __restrict__ W0, float* __restrict__ h, float* __restrict__ c) {
    int i = blockIdx.x * blockDim.x + threadIdx.x;
    if (i < HID) { h[i] = W0[i]; c[i] = 0.f; }
}

__global__ void k_step_init(float* maxv, float* sumexp, float* inp_acc) {
    int i = threadIdx.x;
    if (i == 0) { *maxv = -INFINITY; *sumexp = 0.f; }
    if (i < FEAT) inp_acc[i] = 0.f;
}

// global max of mask_t
__global__ void k_mask_max(const float* __restrict__ mask_t, float* __restrict__ maxv) {
    __shared__ float red[256];
    float m = -INFINITY;
    for (int i = blockIdx.x * blockDim.x + threadIdx.x; i < NN; i += gridDim.x * blockDim.x)
        m = fmaxf(m, mask_t[i]);
    red[threadIdx.x] = m;
    __syncthreads();
    for (int s = 128; s > 0; s >>= 1) {
        if (threadIdx.x < s) red[threadIdx.x] = fmaxf(red[threadIdx.x], red[threadIdx.x + s]);
        __syncthreads();
    }
    if (threadIdx.x == 0) atomicMaxF(maxv, red[0]);
}

// inp_acc[f] += sum_n exp(mask-max)*x[n,f]; sumexp += sum_n exp(mask-max)
// wave-per-node-stride: lane f handles feature f
__global__ void k_wsum(const float* __restrict__ x_t, const float* __restrict__ mask_t,
                       const float* __restrict__ maxv, float* __restrict__ sumexp,
                       float* __restrict__ inp_acc) {
    int lane = threadIdx.x & 63;
    int wib = threadIdx.x >> 6;
    int gw = blockIdx.x * (blockDim.x >> 6) + wib;
    int nw = gridDim.x * (blockDim.x >> 6);
    float mx = *maxv;
    float acc = 0.f, se = 0.f;
    for (int n = gw; n < NN; n += nw) {
        float w = expf(mask_t[n] - mx);
        acc += w * x_t[(size_t)n * FEAT + lane];
        se += w;
    }
    __shared__ float sacc[4][FEAT];
    sacc[wib][lane] = acc;
    __syncthreads();
    if (wib == 0) {
        float a = sacc[0][lane] + sacc[1][lane] + sacc[2][lane] + sacc[3][lane];
        atomicAdd(&inp_acc[lane], a);
    }
    if (lane == 0) atomicAdd(sumexp, se);  // w identical across lanes; one add per wave
}

// gates[row] = W_ih[row]·(inp_acc/sumexp) + W_hh[row]·h + b_ih[row] + b_hh[row]
// one wave per row; float4 loads of the 4096-wide W_hh row
__global__ __launch_bounds__(256) void k_gates(
    const float* __restrict__ Wih, const float* __restrict__ Whh,
    const float* __restrict__ bih, const float* __restrict__ bhh,
    const float* __restrict__ inp_acc, const float* __restrict__ sumexp,
    const float* __restrict__ h, float* __restrict__ gates) {
    int lane = threadIdx.x & 63;
    int row = (blockIdx.x * blockDim.x + threadIdx.x) >> 6;
    if (row >= NGATES) return;
    const float4* wr = (const float4*)(Whh + (size_t)row * HID);
    const float4* h4 = (const float4*)h;
    float acc = 0.f;
    #pragma unroll
    for (int c = 0; c < 16; ++c) {
        float4 w = wr[c * 64 + lane];
        float4 hv = h4[c * 64 + lane];
        acc += w.x * hv.x + w.y * hv.y + w.z * hv.z + w.w * hv.w;
    }
    float inp_part = Wih[(size_t)row * FEAT + lane] * inp_acc[lane];
    float v = acc + inp_part / (*sumexp);
    #pragma unroll
    for (int off = 32; off > 0; off >>= 1) v += __shfl_xor(v, off, 64);
    if (lane == 0) gates[row] = v + bih[row] + bhh[row];
}

// LSTM pointwise: c2 = sig(f)*c + sig(i)*tanh(g); h2 = sig(o)*tanh(c2)
__global__ void k_cell(const float* __restrict__ gates, float* __restrict__ h, float* __restrict__ c) {
    int u = blockIdx.x * blockDim.x + threadIdx.x;
    if (u >= HID) return;
    float ig = gates[u], fg = gates[HID + u], gg = gates[2 * HID + u], og = gates[3 * HID + u];
    float si = 1.f / (1.f + expf(-ig));
    float sf = 1.f / (1.f + expf(-fg));
    float so = 1.f / (1.f + expf(-og));
    float c2 = sf * c[u] + si * tanhf(gg);
    float h2 = so * tanhf(c2);
    c[u] = c2; h[u] = h2;
}

// hfeat = x @ W (W = h_state as [64][64]); al/ar = hfeat·att_{l,r};
// also init m=-inf, denom=0, out_t=0
__global__ __launch_bounds__(256) void k_feat(
    const float* __restrict__ x_t, const float* __restrict__ Wm, const float* __restrict__ att,
    float* __restrict__ hfeat, float* __restrict__ al, float* __restrict__ ar,
    float* __restrict__ m, float* __restrict__ denom, float* __restrict__ out_t) {
    __shared__ float Wl[HID];
    __shared__ float attS[2 * FEAT];
    for (int i = threadIdx.x; i < HID; i += 256) Wl[i] = Wm[i];
    if (threadIdx.x < 2 * FEAT) attS[threadIdx.x] = att[threadIdx.x];
    __syncthreads();
    int n = blockIdx.x * 256 + threadIdx.x;
    if (n >= NN) return;
    float acc[FEAT];
    #pragma unroll
    for (int o = 0; o < FEAT; ++o) acc[o] = 0.f;
    const float4* x4 = (const float4*)(x_t + (size_t)n * FEAT);
    for (int k4 = 0; k4 < 16; ++k4) {
        float4 xv = x4[k4];
        const float* w0 = &Wl[(k4 * 4 + 0) * FEAT];
        const float* w1 = &Wl[(k4 * 4 + 1) * FEAT];
        const float* w2 = &Wl[(k4 * 4 + 2) * FEAT];
        const float* w3 = &Wl[(k4 * 4 + 3) * FEAT];
        #pragma unroll
        for (int o = 0; o < FEAT; ++o)
            acc[o] += xv.x * w0[o] + xv.y * w1[o] + xv.z * w2[o] + xv.w * w3[o];
    }
    float aL = 0.f, aR = 0.f;
    #pragma unroll
    for (int o = 0; o < FEAT; ++o) { aL += acc[o] * attS[o]; aR += acc[o] * attS[FEAT + o]; }
    float4* hf = (float4*)(hfeat + (size_t)n * FEAT);
    float4* ot = (float4*)(out_t + (size_t)n * FEAT);
    #pragma unroll
    for (int o4 = 0; o4 < 16; ++o4) {
        hf[o4] = make_float4(acc[o4 * 4], acc[o4 * 4 + 1], acc[o4 * 4 + 2], acc[o4 * 4 + 3]);
        ot[o4] = make_float4(0.f, 0.f, 0.f, 0.f);
    }
    al[n] = aL; ar[n] = aR; m[n] = -INFINITY; denom[n] = 0.f;
}

// pass 1: e = leaky_relu(al[src]+ar[dst]); segment max over dst
__global__ void k_edge1(const int* __restrict__ src, const int* __restrict__ dst,
                        const float* __restrict__ al, const float* __restrict__ ar,
                        float* __restrict__ e_buf, float* __restrict__ m) {
    int i = blockIdx.x * blockDim.x + threadIdx.x;
    if (i >= NE) return;
    float e = al[src[i]] + ar[dst[i]];
    e = e >= 0.f ? e : NEG_SLOPE * e;
    e_buf[i] = e;
    atomicMaxF(&m[dst[i]], e);
}

// pass 2: ex = exp(e - m[dst]); denom[dst] += ex (e_buf overwritten in place)
__global__ void k_edge2(const int* __restrict__ dst, float* __restrict__ e_buf,
                        const float* __restrict__ m, float* __restrict__ denom) {
    int i = blockIdx.x * blockDim.x + threadIdx.x;
    if (i >= NE) return;
    int d = dst[i];
    float ex = expf(e_buf[i] - m[d]);
    e_buf[i] = ex;
    atomicAdd(&denom[d], ex);
}

// pass 3: out[dst] += (ex/denom[dst])*ew * hfeat[src]  — one wave per edge, lane = feature
__global__ __launch_bounds__(256) void k_edge3(
    const int* __restrict__ src, const int* __restrict__ dst, const float* __restrict__ ew,
    const float* __restrict__ e_buf, const float* __restrict__ denom,
    const float* __restrict__ hfeat, float* __restrict__ out_t) {
    int lane = threadIdx.x & 63;
    int eid = (int)(((size_t)blockIdx.x * blockDim.x + threadIdx.x) >> 6);
    if (eid >= NE) return;
    int s = src[eid], d = dst[eid];
    float coef = e_buf[eid] / (denom[d] + 1e-16f) * ew[eid];
    atomicAdd(&out_t[(size_t)d * FEAT + lane], coef * hfeat[(size_t)s * FEAT + lane]);
}

extern "C" void kernel_launch(void* const* d_in, const int* in_sizes, int n_in,
                              void* d_out, int out_size, void* d_ws, size_t ws_size,
                              hipStream_t stream) {
    const float* node_embs   = (const float*)d_in[0];
    const float* mask        = (const float*)d_in[1];
    const int*   edge_index  = (const int*)d_in[2];
    const float* edge_weight = (const float*)d_in[3];
    const float* Wih         = (const float*)d_in[4];
    const float* Whh         = (const float*)d_in[5];
    const float* bih         = (const float*)d_in[6];
    const float* bhh         = (const float*)d_in[7];
    const float* W0          = (const float*)d_in[8];
    const float* att         = (const float*)d_in[9];
    float* out = (float*)d_out;
    float* ws  = (float*)d_ws;

    // workspace layout (floats)
    float* h_state = ws;              // 4096
    float* c_state = ws + 4096;       // 4096
    float* gates   = ws + 8192;       // 16384
    float* maxv    = ws + 24576;      // 1
    float* sumexp  = ws + 24577;      // 1
    float* inp_acc = ws + 24578;      // 64
    float* al      = ws + 24704;      // 50000
    float* ar      = ws + 74704;      // 50000
    float* mbuf    = ws + 124704;     // 50000
    float* denom   = ws + 174704;     // 50000
    float* e_buf   = ws + 224704;     // 800000
    float* hfeat   = ws + 1024704;    // 3200000   (~16.9 MB total)

    k_init<<<(HID + 255) / 256, 256, 0, stream>>>(W0, h_state, c_state);

    for (int t = 0; t < T_STEPS; ++t) {
        const float* x_t    = node_embs + (size_t)t * NN * FEAT;
        const float* mask_t = mask + (size_t)t * NN;
        const int*   src    = edge_index + (size_t)t * 2 * NE;
        const int*   dst    = src + NE;
        const float* ew     = edge_weight + (size_t)t * NE;
        float*       out_t  = out + (size_t)t * NN * FEAT;

        k_step_init<<<1, 128, 0, stream>>>(maxv, sumexp, inp_acc);
        k_mask_max<<<128, 256, 0, stream>>>(mask_t, maxv);
        k_wsum<<<128, 256, 0, stream>>>(x_t, mask_t, maxv, sumexp, inp_acc);
        k_gates<<<NGATES / 4, 256, 0, stream>>>(Wih, Whh, bih, bhh, inp_acc, sumexp, h_state, gates);
        k_cell<<<(HID + 255) / 256, 256, 0, stream>>>(gates, h_state, c_state);
        k_feat<<<(NN + 255) / 256, 256, 0, stream>>>(x_t, h_state, att, hfeat, al, ar, mbuf, denom, out_t);
        k_edge1<<<(NE + 255) / 256, 256, 0, stream>>>(src, dst, al, ar, e_buf, mbuf);
        k_edge2<<<(NE + 255) / 256, 256, 0, stream>>>(dst, e_buf, mbuf, denom);
        k_edge3<<<(int)(((size_t)NE * FEAT + 255) / 256), 256, 0, stream>>>(src, dst, ew, e_buf, denom, hfeat, out_t);
    }
}